// Round 11
// baseline (151.422 us; speedup 1.0000x reference)
//
#include <hip/hip_runtime.h>
#include <hip/hip_bf16.h>

// MessagePassing: out[col[e]] += x[row[e]], x: [N=50000, D=128] f32.
// Budget: dur_us = ~60us harness poison floor + pipeline (~64us @ R10).
// Gather is the dominant term and is bound on L2-miss random-row traffic:
// xb rows (256B) re-read ~10x from random XCDs -> per-XCD L2 (4MiB) can't
// hold the 12.8MB table, reads drain from L3/HBM.
// R11: feature-slice XCD affinity. 4 slices x 32 feats; slice of xb = 3.2MB
// fits ONE XCD's L2. blockIdx swizzled so slice s runs on XCDs {2s,2s+1}
// (bid%8 -> XCD heuristic); each edge-slice read is exactly one 64B line.
// Also 4x wave count (200k) for latency hiding.

#define D_FEAT 128
#define MAXDEG 32   // Poisson(10) max deg over 50k nodes ~26; deg>32 -> ovf list

typedef unsigned short u16;
typedef unsigned int u32;

__device__ __forceinline__ u16 f2bf(float f) {
    union { __hip_bfloat16 h; u16 u; } c;
    c.h = __float2bfloat16(f);   // RNE
    return c.u;
}
__device__ __forceinline__ float bflo(u32 u) { return __uint_as_float(u << 16); }
__device__ __forceinline__ float bfhi(u32 u) { return __uint_as_float(u & 0xffff0000u); }

// ---------------- fused: fill buckets (blocks [0,FB)) + convert x->bf16 ----------------
__global__ __launch_bounds__(256) void fused_kernel(const float* __restrict__ x,
                                                    u16* __restrict__ xb, int nf4,
                                                    const int* __restrict__ row,
                                                    const int* __restrict__ col,
                                                    int* __restrict__ cnt,
                                                    u16* __restrict__ srclist,
                                                    int* __restrict__ ovf,
                                                    int* __restrict__ ovfcnt,
                                                    int E, int ovfcap,
                                                    int fill_blocks, int aligned) {
    if ((int)blockIdx.x < fill_blocks) {
        // ---- fill: 4 edges/thread, 4 independent atomic chains ----
        const int t = blockIdx.x * 256 + threadIdx.x;
        const int e0 = t * 4;
        if (e0 >= E) return;
        int d[4], s[4], p[4], ne;
        if (aligned && e0 + 4 <= E) {
            const int4 dv = *reinterpret_cast<const int4*>(col + e0);
            const int4 sv = *reinterpret_cast<const int4*>(row + e0);
            d[0] = dv.x; d[1] = dv.y; d[2] = dv.z; d[3] = dv.w;
            s[0] = sv.x; s[1] = sv.y; s[2] = sv.z; s[3] = sv.w;
            ne = 4;
        } else {
            ne = E - e0; if (ne > 4) ne = 4;
            for (int k = 0; k < ne; ++k) { d[k] = col[e0 + k]; s[k] = row[e0 + k]; }
        }
        #pragma unroll
        for (int k = 0; k < 4; ++k)
            if (k < ne) p[k] = atomicAdd(&cnt[d[k]], 1);
        #pragma unroll
        for (int k = 0; k < 4; ++k) {
            if (k < ne) {
                if (p[k] < MAXDEG) {
                    srclist[(size_t)d[k] * MAXDEG + p[k]] = (u16)s[k];
                } else {
                    int o = atomicAdd(ovfcnt, 1);
                    if (o < ovfcap) { ovf[2 * o] = d[k]; ovf[2 * o + 1] = s[k]; }
                }
            }
        }
    } else {
        // ---- convert: float4 -> 4x bf16 ----
        const int i = ((int)blockIdx.x - fill_blocks) * 256 + threadIdx.x;
        if (i < nf4) {
            const float4 v = reinterpret_cast<const float4*>(x)[i];
            ushort4 o;
            o.x = f2bf(v.x); o.y = f2bf(v.y); o.z = f2bf(v.z); o.w = f2bf(v.w);
            reinterpret_cast<ushort4*>(xb)[i] = o;
        }
    }
}

// ---------------- gather: one wave per (node, 32-feat slice) ----------------
// Grid swizzle: xcd = bid&7, slice = xcd>>1, group = (bid>>3)*2 + (bid&1).
// Wave w of the block handles node = group*4 + w, slice fixed per block.
// Quarter q (16 lanes) owns one edge per step; lane loads one dword (2 bf16)
// -> each edge-slice read is one 64B line. All __shfl executed with the full
// wave active (R9 lesson: shfl source from exec-masked lane is undefined).
__global__ __launch_bounds__(256) void gathers_kernel(const u16* __restrict__ xb,
                                                      const int* __restrict__ cnt,
                                                      const u16* __restrict__ srclist,
                                                      const int* __restrict__ ovf,
                                                      const int* __restrict__ ovfcnt,
                                                      float* __restrict__ out,
                                                      int N, int ovfcap) {
    const int bid   = blockIdx.x;
    const int xcd   = bid & 7;
    const int slice = xcd >> 1;                       // 0..3
    const int group = ((bid >> 3) << 1) | (bid & 1);  // dense per slice
    const int wav   = threadIdx.x >> 6;               // 0..3
    const int wid   = group * 4 + wav;                // node id
    if (wid >= N) return;
    const int lane = threadIdx.x & 63;
    const int q  = lane >> 4;                         // quarter 0..3
    const int c2 = lane & 15;                         // dword column in slice

    const int rawdeg = cnt[wid];
    const int deg = rawdeg > MAXDEG ? MAXDEG : rawdeg;
    const u16* bucket = srclist + (size_t)wid * MAXDEG;
    const int bval = (int)bucket[lane & 31];          // 64B bucket per wave

    const size_t colbase = (size_t)slice * 32 + (size_t)c2 * 2;  // u16 units
    float a0 = 0.f, a1 = 0.f;

    int j = 0;
    for (; j + 8 <= deg; j += 8) {                    // wave-uniform
        const int i0 = __shfl(bval, j + q, 64);
        const int i1 = __shfl(bval, j + 4 + q, 64);
        const u32 w0 = *reinterpret_cast<const u32*>(xb + (size_t)i0 * D_FEAT + colbase);
        const u32 w1 = *reinterpret_cast<const u32*>(xb + (size_t)i1 * D_FEAT + colbase);
        a0 += bflo(w0) + bflo(w1);
        a1 += bfhi(w0) + bfhi(w1);
    }
    if (j + 4 <= deg) {                               // wave-uniform
        const int i0 = __shfl(bval, j + q, 64);
        const u32 w0 = *reinterpret_cast<const u32*>(xb + (size_t)i0 * D_FEAT + colbase);
        a0 += bflo(w0); a1 += bfhi(w0);
        j += 4;
    }
    {
        const int r = deg - j;                        // 0..3
        const int i0 = __shfl(bval, j + q, 64);       // all lanes shuffle
        if (q < r) {                                  // predicated use only
            const u32 w0 = *reinterpret_cast<const u32*>(xb + (size_t)i0 * D_FEAT + colbase);
            a0 += bflo(w0); a1 += bfhi(w0);
        }
    }

    // inline overflow fixup (deg > MAXDEG nodes only, ~never) — no shfl inside
    if (rawdeg > MAXDEG) {
        int novf = *ovfcnt;
        if (novf > ovfcap) novf = ovfcap;
        for (int k = 0; k < novf; ++k) {
            if (ovf[2 * k] == wid && q == 0) {
                const int s = ovf[2 * k + 1];
                const u32 w = *reinterpret_cast<const u32*>(xb + (size_t)s * D_FEAT + colbase);
                a0 += bflo(w); a1 += bfhi(w);
            }
        }
    }

    // combine the 4 quarters (all lanes active)
    a0 += __shfl_xor(a0, 16, 64);
    a1 += __shfl_xor(a1, 16, 64);
    a0 += __shfl_xor(a0, 32, 64);
    a1 += __shfl_xor(a1, 32, 64);
    if (q == 0) {
        float* o = out + (size_t)wid * D_FEAT + slice * 32 + c2 * 2;
        *reinterpret_cast<float2*>(o) = make_float2(a0, a1);  // 16 lanes x 8B = 128B
    }
}

// ---------------- last-resort fallback: atomic scatter (always correct) ----------------
__global__ void mp_scatter_kernel(const float* __restrict__ x,
                                  const int* __restrict__ row,
                                  const int* __restrict__ col,
                                  float* __restrict__ out, int n_edges) {
    const int t = blockIdx.x * blockDim.x + threadIdx.x;
    const int e = t >> 5;
    const int c = t & 31;
    if (e >= n_edges) return;
    const float4 v = *reinterpret_cast<const float4*>(
        x + (size_t)row[e] * D_FEAT + (size_t)c * 4);
    float* o = out + (size_t)col[e] * D_FEAT + (size_t)c * 4;
    atomicAdd(o + 0, v.x);
    atomicAdd(o + 1, v.y);
    atomicAdd(o + 2, v.z);
    atomicAdd(o + 3, v.w);
}

extern "C" void kernel_launch(void* const* d_in, const int* in_sizes, int n_in,
                              void* d_out, int out_size, void* d_ws, size_t ws_size,
                              hipStream_t stream) {
    const float* x   = (const float*)d_in[0];
    const int*   ei  = (const int*)d_in[1];
    float*       out = (float*)d_out;

    const int E = in_sizes[1] / 2;      // edge_index is [2, E]
    const int N = out_size / D_FEAT;
    const int* row = ei;                 // sources
    const int* col = ei + E;             // targets

    // ws byte layout: cnt[N]+ovfcnt | xb[N*128 u16] | srclist[N*32 u16] | ovf[2E int]
    const size_t cnt_bytes = ((size_t)N + 1) * 4;
    const size_t xb_off    = (cnt_bytes + 255) & ~(size_t)255;
    const size_t xb_bytes  = (size_t)N * D_FEAT * 2;
    const size_t src_off   = (xb_off + xb_bytes + 255) & ~(size_t)255;
    const size_t src_bytes = (size_t)N * MAXDEG * 2;
    const size_t ovf_off   = (src_off + src_bytes + 255) & ~(size_t)255;
    const size_t needed    = ovf_off + 2ull * (size_t)E * 4;

    if (ws_size < needed || N > 65535) {
        (void)hipMemsetAsync(d_out, 0, (size_t)out_size * sizeof(float), stream);
        const int total = E * 32;
        mp_scatter_kernel<<<(total + 255) / 256, 256, 0, stream>>>(x, row, col, out, E);
        return;
    }

    char* wsb     = (char*)d_ws;
    int*  cnt     = (int*)wsb;
    int*  ovfcnt  = cnt + N;
    u16*  xb      = (u16*)(wsb + xb_off);
    u16*  srclist = (u16*)(wsb + src_off);
    int*  ovf     = (int*)(wsb + ovf_off);

    // 1. zero counters (cnt[N] + ovfcnt)
    (void)hipMemsetAsync(cnt, 0, cnt_bytes, stream);

    // 2. fused fill + convert (fill blocks first so their atomic latency
    //    hides under the convert blocks' streaming)
    const int fill_threads = (E + 3) / 4;
    const int fill_blocks  = (fill_threads + 255) / 256;
    const int nf4          = N * D_FEAT / 4;
    const int conv_blocks  = (nf4 + 255) / 256;
    const int aligned      = ((E & 3) == 0) ? 1 : 0;
    fused_kernel<<<fill_blocks + conv_blocks, 256, 0, stream>>>(
        x, xb, nf4, row, col, cnt, srclist, ovf, ovfcnt, E, E, fill_blocks, aligned);

    // 3. slice gather: 4 waves (nodes) per block, slice = (bid&7)>>1
    const int blocks_per_slice = (N + 3) / 4;           // nodes/4
    const int half             = (blocks_per_slice + 1) / 2;
    const int grid             = 8 * half;
    gathers_kernel<<<grid, 256, 0, stream>>>(xb, cnt, srclist, ovf, ovfcnt, out, N, E);
}